// Round 8
// baseline (381.071 us; speedup 1.0000x reference)
//
#include <hip/hip_runtime.h>
#include <hip/hip_bf16.h>
#include <math.h>

// BS=1, L=2048, D=4096. r16=362.2us, r17=371.2us (regression: chunked swizzle
// + fused transpose net +9us; GEMM2-on-n128 time-neutral but FETCH 49->139MB).
// r18 (resubmit; r7 was infra flake GPUAcquisitionTimeout — kernel unbenched;
// line-by-line audit passed: MFMA coverage, epilogue bijectivity, CMODE2
// atomic partials, ledger unchanged from verified r16):
// (1) gemm_n128 waves re-partitioned 2Mx4N (128x32) -> 4Mx2N (64x64):
// frag reuse R_a=R_b=4, LDS bytes/MFMA 0.625->0.5KB, per-tile LDS 160->128KB,
// ds_reads/wave 20->16. LDS-read-bound ceiling 48%->62% MfmaUtil (r17 PMC:
// MfmaUtil 37%, VALUBusy 23%, conflicts 0, occ 19% => LDS pipe is limiter).
// (2) XCD swizzle back to r16's proven 2D-region form (4x8; 4x16 for 512).
// (3) transpose/cvt reverted to r16's separate proven kernels.
// GEMM2 stays on gemm_n128<0,5> (proven r17, time-neutral, inherits (1)).

typedef __attribute__((ext_vector_type(8))) short short8;
typedef __attribute__((ext_vector_type(4))) float f32x4;

__device__ __forceinline__ unsigned short f2bf(float f) {
  unsigned u = __float_as_uint(f);
  return (unsigned short)((u + 0x7FFF + ((u >> 16) & 1)) >> 16);  // RNE
}

typedef const __attribute__((address_space(1))) unsigned int* gas_t;
typedef __attribute__((address_space(3))) unsigned int* las_t;
__device__ __forceinline__ void dma16(const unsigned short* g, unsigned short* l)
{
  __builtin_amdgcn_global_load_lds((gas_t)(const void*)g, (las_t)(void*)l,
                                   16, 0, 0);
}

// ---------------------------------------------------------------------------
// BM=256 x BN=128, BK=64, TRIPLE-buffered counted-vmcnt GEMM.
// Grid = (M/256)*(N/128) blocks (256 or 512). LDS 144KiB -> 1 block/CU.
// C[i][j] = sum_k A[i][k]*B[j][k], both bf16 k-major.
// CMODE 0: C fp32. CMODE 1: C bf16. CMODE 2: colsum[j] += sum_i tanh(acc).
// NXBS: log2 grid columns (N/128): 4 -> 16 cols, 5 -> 32 cols.
// r18 wave split: 8 waves as 4Mx2N, wave-tile 64x64 (acc[4][4]).
// Pipeline: compute tile kt from buf kt%3 while kt+1 lands and kt+2 issues.
// One vmcnt(6)+barrier per K-tile (ledger verified r16).
// ---------------------------------------------------------------------------
template<int CMODE, int NXBS>
__global__ __launch_bounds__(512, 2) void gemm_n128(
    const unsigned short* __restrict__ A, const unsigned short* __restrict__ B,
    void* __restrict__ Cv, float* __restrict__ colsum,
    int K, int lda, int ldb, int ldc)
{
  // chunks: c0..c3 = A rows c*64 (32KiB); c4,c5 = B rows (c-4)*64 (16KiB)
  __shared__ unsigned short sm[3][384 * 64];   // 3 x 48KiB
  const int t = threadIdx.x;
  const int lane = t & 63, wid = t >> 6;
  const int wr = wid >> 1;          // 0..3 (M quarter: 64 rows)
  const int wc = wid & 1;           // 0..1 (N half: 64 cols)
  const int lr = lane & 15, lq = lane >> 4;

  // r16-style 2D-region XCD swizzle: XCD x gets a compact region
  // (4x8 tiles for 16-col grids, 4x16 for 32-col grids). Bijective.
  int bx, by;
  {
    int wg = blockIdx.x;
    int x = wg & 7, s = wg >> 3;
    if (NXBS == 4) { by = (x & 3) * 4 + (s >> 3); bx = (x >> 2) * 8 + (s & 7); }
    else           { by = (x & 3) * 4 + (s >> 4); bx = (x >> 2) * 16 + (s & 15); }
  }
  const int i0 = by * 256, j0 = bx * 128;

  const int r_ = t >> 3;                       // row within chunk (0..63)
  const int ss_ = ((t & 7) ^ (r_ & 7)) * 8;    // swizzled source col (elems)

  auto issue = [&](int buf, int c, int k0) {
    const unsigned short* M;
    int ld, r0;
    if (c < 4) { M = A; ld = lda; r0 = i0 + c * 64; }
    else       { M = B; ld = ldb; r0 = j0 + (c - 4) * 64; }
    unsigned short* lb = &sm[buf][c * 4096];
    dma16(M + (size_t)(r0 + r_) * ld + k0 + ss_, lb + wid * 512);
  };

  auto frag = [&](const unsigned short* mat, int row, int kh) -> short8 {
    int lb = row * 128 + kh * 64 + (lq << 4);
    int pb = lb ^ ((row & 7) << 4);
    return *(const short8*)((const char*)mat + pb);
  };

  f32x4 acc[4][4];   // [m][n], wave-tile 64x64
  #pragma unroll
  for (int a = 0; a < 4; a++)
    #pragma unroll
    for (int b = 0; b < 4; b++) acc[a][b] = (f32x4){0.f, 0.f, 0.f, 0.f};

  // Prologue: fully issue tiles 0 and 1; wait for tile 0 (6 left in flight).
  #pragma unroll
  for (int c = 0; c < 6; c++) issue(0, c, 0);
  #pragma unroll
  for (int c = 0; c < 6; c++) issue(1, c, 64);
  asm volatile("s_waitcnt vmcnt(6)" ::: "memory");
  __builtin_amdgcn_s_barrier();

  const int NT = K >> 6;
  int cur = 0;
  for (int kt = 0; kt < NT; kt++) {
    const unsigned short* As = sm[cur];
    const unsigned short* Bs = sm[cur] + 256 * 64;   // B rows 0..127
    const int b2 = (cur + 2 >= 3) ? cur - 1 : cur + 2;   // (cur+2)%3
    const int kn = (kt + 2) << 6;
    const bool st = (kt + 2 < NT);

    short8 af[2][2], bfr[4][2];
    // ---- q0: A-frags m=0,1 (rows wr*64 + {0,1}*16), all B-frags ----
    #pragma unroll
    for (int m = 0; m < 2; m++) {
      af[m][0] = frag(As, wr * 64 + m * 16 + lr, 0);
      af[m][1] = frag(As, wr * 64 + m * 16 + lr, 1);
    }
    #pragma unroll
    for (int n = 0; n < 4; n++) {
      bfr[n][0] = frag(Bs, wc * 64 + n * 16 + lr, 0);
      bfr[n][1] = frag(Bs, wc * 64 + n * 16 + lr, 1);
    }
    if (st) {
      issue(b2, 0, kn); issue(b2, 2, kn);
      issue(b2, 4, kn); issue(b2, 5, kn);
    }
    __builtin_amdgcn_s_setprio(1);
    #pragma unroll
    for (int m = 0; m < 2; m++)
      #pragma unroll
      for (int n = 0; n < 4; n++) {
        acc[m][n] = __builtin_amdgcn_mfma_f32_16x16x32_bf16(
            af[m][0], bfr[n][0], acc[m][n], 0, 0, 0);
        acc[m][n] = __builtin_amdgcn_mfma_f32_16x16x32_bf16(
            af[m][1], bfr[n][1], acc[m][n], 0, 0, 0);
      }
    __builtin_amdgcn_s_setprio(0);

    // ---- q1: A-frags m=2,3 (rows wr*64 + {2,3}*16) ----
    #pragma unroll
    for (int m = 0; m < 2; m++) {
      af[m][0] = frag(As, wr * 64 + (2 + m) * 16 + lr, 0);
      af[m][1] = frag(As, wr * 64 + (2 + m) * 16 + lr, 1);
    }
    if (st) { issue(b2, 1, kn); issue(b2, 3, kn); }
    __builtin_amdgcn_s_setprio(1);
    #pragma unroll
    for (int m = 0; m < 2; m++)
      #pragma unroll
      for (int n = 0; n < 4; n++) {
        acc[2 + m][n] = __builtin_amdgcn_mfma_f32_16x16x32_bf16(
            af[m][0], bfr[n][0], acc[2 + m][n], 0, 0, 0);
        acc[2 + m][n] = __builtin_amdgcn_mfma_f32_16x16x32_bf16(
            af[m][1], bfr[n][1], acc[2 + m][n], 0, 0, 0);
      }
    __builtin_amdgcn_s_setprio(0);

    // ---- end-of-tile: ensure tile kt+1 fully landed before next iter ----
    if (kt + 1 < NT) {
      if (st) asm volatile("s_waitcnt vmcnt(6)" ::: "memory");
      else    asm volatile("s_waitcnt vmcnt(0)" ::: "memory");
      __builtin_amdgcn_s_barrier();
    }
    cur = (cur + 1 == 3) ? 0 : cur + 1;
  }

  if (CMODE == 2) {
    // C/D layout: col=lane&15, row=lq*4+reg.
    #pragma unroll
    for (int n = 0; n < 4; n++) {
      float s = 0.f;
      #pragma unroll
      for (int m = 0; m < 4; m++)
        #pragma unroll
        for (int r = 0; r < 4; r++) s += tanhf(acc[m][n][r]);
      s += __shfl_xor(s, 16);
      s += __shfl_xor(s, 32);
      if (lq == 0) atomicAdd(&colsum[j0 + wc * 64 + n * 16 + lr], s);
    }
  } else {
    #pragma unroll
    for (int m = 0; m < 4; m++)
      #pragma unroll
      for (int n = 0; n < 4; n++)
        #pragma unroll
        for (int r = 0; r < 4; r++) {
          int row = i0 + wr * 64 + m * 16 + lq * 4 + r;
          int col = j0 + wc * 64 + n * 16 + lr;
          if (CMODE == 0)
            ((float*)Cv)[(size_t)row * ldc + col] = acc[m][n][r];
          else
            ((unsigned short*)Cv)[(size_t)row * ldc + col] = f2bf(acc[m][n][r]);
        }
  }
}

// 128x128-tile bf16 MFMA GEMM (legacy path for non-pre tiers / R<4096).
template<int BF32, int CMODE>
__global__ __launch_bounds__(256) void mfma_gemm(
    const unsigned short* __restrict__ Abf, const void* __restrict__ Bv,
    void* __restrict__ Cv, float* __restrict__ colsum,
    int K, int lda, int ldb, int ldc)
{
  __shared__ unsigned short As[128 * 32];
  __shared__ unsigned short Bs[128 * 32];
  const int t = threadIdx.x;
  const int lane = t & 63, wid = t >> 6;
  const int wm = (wid >> 1) * 64, wn = (wid & 1) * 64;
  const int i0 = blockIdx.y * 128, j0 = blockIdx.x * 128;
  const int lr = lane & 15, lq = lane >> 4;

  f32x4 acc[4][4];
  #pragma unroll
  for (int a = 0; a < 4; a++)
    #pragma unroll
    for (int b = 0; b < 4; b++) acc[a][b] = (f32x4){0.f, 0.f, 0.f, 0.f};

  for (int k0 = 0; k0 < K; k0 += 32) {
    #pragma unroll
    for (int u = 0; u < 2; u++) {
      int vid = u * 256 + t;
      int row = vid >> 2, kq = (vid & 3) * 8;
      dma16(Abf + (size_t)(i0 + row) * lda + k0 + kq,
            &As[(u * 256 + wid * 64) * 8]);
    }
    if (BF32 == 0) {
      #pragma unroll
      for (int u = 0; u < 2; u++) {
        int vid = u * 256 + t;
        int row = vid >> 2, kq = (vid & 3) * 8;
        dma16((const unsigned short*)Bv + (size_t)(j0 + row) * ldb + k0 + kq,
              &Bs[(u * 256 + wid * 64) * 8]);
      }
    } else {
      #pragma unroll
      for (int u = 0; u < 2; u++) {
        int vid = u * 256 + t;
        int row = vid >> 2, kq = (vid & 3) * 8;
        const float* s = (const float*)Bv + (size_t)(j0 + row) * ldb + k0 + kq;
        float4 f0 = *(const float4*)s;
        float4 f1 = *(const float4*)(s + 4);
        union { unsigned short h[8]; int4 v; } pk;
        pk.h[0] = f2bf(f0.x); pk.h[1] = f2bf(f0.y);
        pk.h[2] = f2bf(f0.z); pk.h[3] = f2bf(f0.w);
        pk.h[4] = f2bf(f1.x); pk.h[5] = f2bf(f1.y);
        pk.h[6] = f2bf(f1.z); pk.h[7] = f2bf(f1.w);
        *(int4*)&Bs[(size_t)vid * 8] = pk.v;
      }
    }
    __syncthreads();

    short8 af[4], bfr[4];
    #pragma unroll
    for (int tm = 0; tm < 4; tm++)
      af[tm] = *(const short8*)&As[(wm + tm * 16 + lr) * 32 + lq * 8];
    #pragma unroll
    for (int tn = 0; tn < 4; tn++)
      bfr[tn] = *(const short8*)&Bs[(wn + tn * 16 + lr) * 32 + lq * 8];

    #pragma unroll
    for (int tm = 0; tm < 4; tm++)
      #pragma unroll
      for (int tn = 0; tn < 4; tn++)
        acc[tm][tn] = __builtin_amdgcn_mfma_f32_16x16x32_bf16(
            af[tm], bfr[tn], acc[tm][tn], 0, 0, 0);
    __syncthreads();
  }

  if (CMODE == 2) {
    #pragma unroll
    for (int tn = 0; tn < 4; tn++) {
      float s = 0.f;
      #pragma unroll
      for (int tm = 0; tm < 4; tm++)
        #pragma unroll
        for (int r = 0; r < 4; r++) s += tanhf(acc[tm][tn][r]);
      s += __shfl_xor(s, 16);
      s += __shfl_xor(s, 32);
      if (lq == 0) atomicAdd(&colsum[j0 + wn + tn * 16 + lr], s);
    }
  } else {
    #pragma unroll
    for (int tm = 0; tm < 4; tm++)
      #pragma unroll
      for (int tn = 0; tn < 4; tn++)
        #pragma unroll
        for (int r = 0; r < 4; r++) {
          int row = i0 + wm + tm * 16 + lq * 4 + r;
          int col = j0 + wn + tn * 16 + lr;
          if (CMODE == 0)
            ((float*)Cv)[(size_t)row * ldc + col] = acc[tm][tn][r];
          else
            ((unsigned short*)Cv)[(size_t)row * ldc + col] = f2bf(acc[tm][tn][r]);
        }
  }
}

// Tt_bf[key][l] = bf16(T[l][key]); T [2048][4096] fp32.
__global__ __launch_bounds__(256) void transpose_bf16(
    const float* __restrict__ T, unsigned short* __restrict__ Tt)
{
  __shared__ float tile[64][65];
  const int tx = threadIdx.x & 63;
  const int ty = threadIdx.x >> 6;
  const int k0 = blockIdx.x * 64;
  const int l0 = blockIdx.y * 64;
  #pragma unroll
  for (int u = 0; u < 16; u++) {
    int row = ty * 16 + u;
    tile[row][tx] = T[(size_t)(l0 + row) * 4096 + k0 + tx];
  }
  __syncthreads();
  #pragma unroll
  for (int u = 0; u < 16; u++) {
    int row = ty * 16 + u;
    Tt[(size_t)(k0 + row) * 2048 + l0 + tx] = f2bf(tile[tx][row]);
  }
}

// out[i] = bf16(in[i]), 8 elements/thread, packed 16B stores.
__global__ __launch_bounds__(256) void cvt_bf16(
    const float* __restrict__ in, unsigned short* __restrict__ out, int n8)
{
  int i = blockIdx.x * 256 + threadIdx.x;
  if (i >= n8) return;
  float4 f0 = ((const float4*)in)[(size_t)i * 2];
  float4 f1 = ((const float4*)in)[(size_t)i * 2 + 1];
  union { unsigned short h[8]; int4 v; } pk;
  pk.h[0] = f2bf(f0.x); pk.h[1] = f2bf(f0.y);
  pk.h[2] = f2bf(f0.z); pk.h[3] = f2bf(f0.w);
  pk.h[4] = f2bf(f1.x); pk.h[5] = f2bf(f1.y);
  pk.h[6] = f2bf(f1.z); pk.h[7] = f2bf(f1.w);
  ((int4*)out)[i] = pk.v;
}

// Row softmax over 4096 fp32, writes bf16 IN PLACE at row start.
__global__ __launch_bounds__(256) void softmax_bf16(float* __restrict__ S)
{
  float* p = S + (size_t)blockIdx.x * 4096;
  const int tid = threadIdx.x;
  float4 v[4];
  #pragma unroll
  for (int u = 0; u < 4; u++) v[u] = ((const float4*)p)[tid * 4 + u];

  float m = -3.4e38f;
  #pragma unroll
  for (int u = 0; u < 4; u++)
    m = fmaxf(m, fmaxf(fmaxf(v[u].x, v[u].y), fmaxf(v[u].z, v[u].w)));
  #pragma unroll
  for (int off = 32; off > 0; off >>= 1) m = fmaxf(m, __shfl_down(m, off, 64));
  __shared__ float redm[4];
  if ((tid & 63) == 0) redm[tid >> 6] = m;
  __syncthreads();
  m = fmaxf(fmaxf(redm[0], redm[1]), fmaxf(redm[2], redm[3]));

  float s = 0.f;
  #pragma unroll
  for (int u = 0; u < 4; u++) {
    v[u].x = __expf(v[u].x - m); v[u].y = __expf(v[u].y - m);
    v[u].z = __expf(v[u].z - m); v[u].w = __expf(v[u].w - m);
    s += v[u].x + v[u].y + v[u].z + v[u].w;
  }
  #pragma unroll
  for (int off = 32; off > 0; off >>= 1) s += __shfl_down(s, off, 64);
  __shared__ float reds[4];
  if ((tid & 63) == 0) reds[tid >> 6] = s;
  __syncthreads();
  s = reds[0] + reds[1] + reds[2] + reds[3];
  const float inv = 1.f / s;

  unsigned short* a = (unsigned short*)p;
  #pragma unroll
  for (int h = 0; h < 2; h++) {
    union { unsigned short u[8]; int4 q; } pk;
    #pragma unroll
    for (int j = 0; j < 2; j++) {
      float4 w = v[h * 2 + j];
      pk.u[j * 4 + 0] = f2bf(w.x * inv); pk.u[j * 4 + 1] = f2bf(w.y * inv);
      pk.u[j * 4 + 2] = f2bf(w.z * inv); pk.u[j * 4 + 3] = f2bf(w.w * inv);
    }
    ((int4*)a)[tid * 2 + h] = pk.q;
  }
}

__global__ void zero_k(float* p, int n)
{
  int i = blockIdx.x * 256 + threadIdx.x;
  if (i < n) p[i] = 0.f;
}

// scores /= max; softmax; -> FP32 out (2048).
__global__ __launch_bounds__(256) void finalize_k(const float* __restrict__ scores,
                                                  float* __restrict__ out)
{
  const int tid = threadIdx.x;
  float s[8];
  #pragma unroll
  for (int u = 0; u < 8; u++) s[u] = scores[tid + u * 256];

  __shared__ float red[4];

  float m = -3.4e38f;
  #pragma unroll
  for (int u = 0; u < 8; u++) m = fmaxf(m, s[u]);
  #pragma unroll
  for (int off = 32; off > 0; off >>= 1) m = fmaxf(m, __shfl_down(m, off, 64));
  if ((tid & 63) == 0) red[tid >> 6] = m;
  __syncthreads();
  m = fmaxf(fmaxf(red[0], red[1]), fmaxf(red[2], red[3]));
  __syncthreads();

  const float inv1 = 1.f / m;
  #pragma unroll
  for (int u = 0; u < 8; u++) s[u] *= inv1;

  float m2 = -3.4e38f;
  #pragma unroll
  for (int u = 0; u < 8; u++) m2 = fmaxf(m2, s[u]);
  #pragma unroll
  for (int off = 32; off > 0; off >>= 1) m2 = fmaxf(m2, __shfl_down(m2, off, 64));
  if ((tid & 63) == 0) red[tid >> 6] = m2;
  __syncthreads();
  m2 = fmaxf(fmaxf(red[0], red[1]), fmaxf(red[2], red[3]));
  __syncthreads();

  float sum = 0.f;
  #pragma unroll
  for (int u = 0; u < 8; u++) { s[u] = expf(s[u] - m2); sum += s[u]; }
  #pragma unroll
  for (int off = 32; off > 0; off >>= 1) sum += __shfl_down(sum, off, 64);
  if ((tid & 63) == 0) red[tid >> 6] = sum;
  __syncthreads();
  sum = red[0] + red[1] + red[2] + red[3];

  const float invs = 1.f / sum;
  #pragma unroll
  for (int u = 0; u < 8; u++)
    out[tid + u * 256] = s[u] * invs;
}

extern "C" void kernel_launch(void* const* d_in, const int* in_sizes, int n_in,
                              void* d_out, int out_size, void* d_ws, size_t ws_size,
                              hipStream_t stream)
{
  const float* T    = (const float*)d_in[0];   // [2048][4096]
  const float* Win  = (const float*)d_in[1];   // [2048][2048] 'ml'
  const float* Wout = (const float*)d_in[2];   // [2048][4096] 'lc'
  float* out = (float*)d_out;

  const size_t FIX1 = 92274688ull + 16384;
  int R = 1024; bool pre = false;
  if      (ws_size >= FIX1 + (size_t)4096 * 16384) { pre = true; R = 4096; }
  else if (ws_size >= FIX1 + (size_t)2048 * 16384) { pre = true; R = 2048; }
  else if (ws_size >= FIX1 + (size_t)1024 * 16384) { pre = true; R = 1024; }

  unsigned short* Tt = (unsigned short*)d_ws;

  if (pre) {
    unsigned short* Tb    = Tt + (size_t)4096 * 2048;
    unsigned short* Winb  = Tb + (size_t)2048 * 4096;
    unsigned short* Woutb = Winb + (size_t)2048 * 2048;
    unsigned short* comb  = Woutb + (size_t)2048 * 4096;
    float* S      = (float*)(comb + (size_t)4096 * 4096);
    float* scores = S + (size_t)R * 4096;

    zero_k<<<8, 256, 0, stream>>>(scores, 2048);
    transpose_bf16<<<dim3(64, 32), 256, 0, stream>>>(T, Tt);
    cvt_bf16<<<4096, 256, 0, stream>>>(T, Tb, 1048576);
    cvt_bf16<<<2048, 256, 0, stream>>>(Win, Winb, 524288);
    cvt_bf16<<<4096, 256, 0, stream>>>(Wout, Woutb, 1048576);

    // GEMM1: Q -> comb[:,2048:]  (M=4096,N=2048,K=2048; 16x16 grid)
    gemm_n128<1, 4><<<256, 512, 0, stream>>>(
        Tt, Winb, comb + 2048, nullptr, 2048, 2048, 2048, 4096);
    for (int c = 0; c < 4096 / R; c++) {
      const size_t d0 = (size_t)c * R;
      if (R == 4096) {
        // GEMM2 (M=N=4096,K=2048; 16x32 grid = 2 machine rounds), fp32 C
        gemm_n128<0, 5><<<512, 512, 0, stream>>>(
            comb + 2048, Tt, S, nullptr, 2048, 4096, 2048, 4096);
      } else {
        mfma_gemm<0, 0><<<dim3(32, R / 128), 256, 0, stream>>>(
            comb + d0 * 4096 + 2048, Tt, S, nullptr, 2048, 4096, 2048, 4096);
      }
      softmax_bf16<<<R, 256, 0, stream>>>(S);
      if (R == 4096) {
        // GEMM3 (M=4096,N=2048,K=4096; 16x16 grid)
        gemm_n128<1, 4><<<256, 512, 0, stream>>>(
            (unsigned short*)S, Tb, comb, nullptr, 4096, 8192, 4096, 4096);
      } else {
        mfma_gemm<0, 1><<<dim3(16, R / 128), 256, 0, stream>>>(
            (unsigned short*)S, Tb, comb + d0 * 4096, nullptr, 4096, 8192, 4096, 4096);
      }
    }
    // GEMM4 (M=4096,N=2048,K=4096, tanh colsum; 16x16 grid)
    gemm_n128<2, 4><<<256, 512, 0, stream>>>(
        comb, Woutb, nullptr, scores, 4096, 4096, 4096, 4096);
    finalize_k<<<1, 256, 0, stream>>>(scores, out);
  } else {
    // tier0: r12 layout (67,117,056 B proven to fit), inline cvt for fp32 B.
    unsigned short* comb = Tt + (size_t)4096 * 2048;
    float* S      = (float*)(comb + (size_t)4096 * 4096);
    float* scores = S + (size_t)1024 * 4096;

    zero_k<<<8, 256, 0, stream>>>(scores, 2048);
    transpose_bf16<<<dim3(64, 32), 256, 0, stream>>>(T, Tt);

    mfma_gemm<1, 1><<<dim3(16, 32), 256, 0, stream>>>(
        Tt, Win, comb + 2048, nullptr, 2048, 2048, 2048, 4096);
    for (int c = 0; c < 4; c++) {
      const size_t d0 = (size_t)c * 1024;
      mfma_gemm<0, 0><<<dim3(32, 8), 256, 0, stream>>>(
          comb + d0 * 4096 + 2048, Tt, S, nullptr, 2048, 4096, 2048, 4096);
      softmax_bf16<<<1024, 256, 0, stream>>>(S);
      mfma_gemm<1, 1><<<dim3(16, 8), 256, 0, stream>>>(
          (unsigned short*)S, T, comb + d0 * 4096, nullptr, 4096, 8192, 4096, 4096);
    }
    mfma_gemm<1, 2><<<dim3(16, 32), 256, 0, stream>>>(
        comb, Wout, nullptr, scores, 4096, 4096, 4096, 4096);
    finalize_k<<<1, 256, 0, stream>>>(scores, out);
  }
}

// Round 9
// 370.717 us; speedup vs baseline: 1.0279x; 1.0279x over previous
//
#include <hip/hip_runtime.h>
#include <hip/hip_bf16.h>
#include <math.h>

// BS=1, L=2048, D=4096. History: r16=362.2us (BEST), r17=371.2 (3-change
// bundle regressed; chunked swizzle blew GEMM2 FETCH 49->139MB), r18=381.1
// (4Mx2N wave split DISPROVEN: MfmaUtil stayed 37%, GEMM1/3/4 +3-4us each).
// Invariant found: GEMM2 = 74.0-74.7us (~920 TF) under 3 different schedules
// -> schedule-family plateau, not LDS/HBM/conflict-bound.
// r19: exact r16 configuration (gemm256 4-phase for GEMM2; tri-buffered
// 2Mx4N gemm_n128 for GEMM1/3/4; r16 region swizzle) + ONE isolated delta:
// transpose_cvt_bf16 fusion (verified in r17) deletes the separate 67MB
// cvt_bf16(T->Tb) read. Predict 362.2 -> ~352-356us, GEMM counters unchanged.

typedef __attribute__((ext_vector_type(8))) short short8;
typedef __attribute__((ext_vector_type(4))) float f32x4;

__device__ __forceinline__ unsigned short f2bf(float f) {
  unsigned u = __float_as_uint(f);
  return (unsigned short)((u + 0x7FFF + ((u >> 16) & 1)) >> 16);  // RNE
}

typedef const __attribute__((address_space(1))) unsigned int* gas_t;
typedef __attribute__((address_space(3))) unsigned int* las_t;
__device__ __forceinline__ void dma16(const unsigned short* g, unsigned short* l)
{
  __builtin_amdgcn_global_load_lds((gas_t)(const void*)g, (las_t)(void*)l,
                                   16, 0, 0);
}

// ---------------------------------------------------------------------------
// 256x256-tile, BK=64, counted-vmcnt 4-phase GEMM (C fp32 out). GEMM2 only.
// Verified r14b/r16: 74.7us, FETCH 49MB, conflicts 0.
// ---------------------------------------------------------------------------
__global__ __launch_bounds__(512, 2) void gemm256(
    const unsigned short* __restrict__ A, const unsigned short* __restrict__ B,
    float* __restrict__ C, int K, int lda, int ldb, int ldc)
{
  __shared__ unsigned short sm[2][2][256 * 64];
  const int t = threadIdx.x;
  const int lane = t & 63;
  const int wid = t >> 6;
  const int wr = wid >> 2;
  const int wc = wid & 3;
  const int lr = lane & 15, lq = lane >> 4;

  int bx, by;
  {
    int wg = blockIdx.x;
    int x = wg & 7, s = wg >> 3;
    by = (x & 3) * 4 + (s >> 3);
    bx = (x >> 2) * 8 + (s & 7);
  }
  const int i0 = by * 256, j0 = bx * 256;

  const int r_ = t >> 3;
  const int ss_ = ((t & 7) ^ (r_ & 7)) * 8;

  auto issue = [&](int buf, int c, int k0) {
    const unsigned short* M;
    int ld, r0;
    if (c < 4) { M = A; ld = lda; r0 = i0 + (c & 3) * 64; }
    else       { M = B; ld = ldb; r0 = j0 + (c & 3) * 64; }
    unsigned short* lb = &sm[buf][c >> 2][(c & 3) * 4096];
    dma16(M + (size_t)(r0 + r_) * ld + k0 + ss_, lb + wid * 512);
  };

  auto frag = [&](const unsigned short* mat, int row, int kh) -> short8 {
    int lb = row * 128 + kh * 64 + (lq << 4);
    int pb = lb ^ ((row & 7) << 4);
    return *(const short8*)((const char*)mat + pb);
  };

  f32x4 acc[8][4];
  #pragma unroll
  for (int a = 0; a < 8; a++)
    #pragma unroll
    for (int b = 0; b < 4; b++) acc[a][b] = (f32x4){0.f, 0.f, 0.f, 0.f};

  issue(0, 0, 0); issue(0, 2, 0);
  issue(0, 4, 0); issue(0, 5, 0);
  issue(0, 6, 0); issue(0, 7, 0);
  issue(0, 1, 0); issue(0, 3, 0);
  asm volatile("s_waitcnt vmcnt(2)" ::: "memory");
  __builtin_amdgcn_s_barrier();

  const int NT = K >> 6;
  for (int kt = 0; kt < NT; kt++) {
    const int cur = kt & 1;
    const unsigned short* As = sm[cur][0];
    const unsigned short* Bs = sm[cur][1];
    const int kn = (kt + 1) << 6;
    const bool st = (kt + 1 < NT);
    short8 bfr[4][2];

    #pragma unroll
    for (int p = 0; p < 4; p++) {
      short8 a0k0 = frag(As, wr * 128 + (p * 2 + 0) * 16 + lr, 0);
      short8 a0k1 = frag(As, wr * 128 + (p * 2 + 0) * 16 + lr, 1);
      short8 a1k0 = frag(As, wr * 128 + (p * 2 + 1) * 16 + lr, 0);
      short8 a1k1 = frag(As, wr * 128 + (p * 2 + 1) * 16 + lr, 1);
      if (p == 0) {
        #pragma unroll
        for (int nf = 0; nf < 4; nf++) {
          bfr[nf][0] = frag(Bs, wc * 64 + nf * 16 + lr, 0);
          bfr[nf][1] = frag(Bs, wc * 64 + nf * 16 + lr, 1);
        }
      }
      if (st) {
        if (p == 0) { issue(cur ^ 1, 0, kn); issue(cur ^ 1, 2, kn); }
        if (p == 1) { issue(cur ^ 1, 4, kn); issue(cur ^ 1, 5, kn); }
        if (p == 2) { issue(cur ^ 1, 6, kn); issue(cur ^ 1, 7, kn); }
        if (p == 3) { issue(cur ^ 1, 1, kn); issue(cur ^ 1, 3, kn); }
      }
      asm volatile("" ::: "memory");
      __builtin_amdgcn_s_barrier();
      __builtin_amdgcn_s_setprio(1);
      #pragma unroll
      for (int nf = 0; nf < 4; nf++) {
        acc[p * 2 + 0][nf] = __builtin_amdgcn_mfma_f32_16x16x32_bf16(
            a0k0, bfr[nf][0], acc[p * 2 + 0][nf], 0, 0, 0);
        acc[p * 2 + 0][nf] = __builtin_amdgcn_mfma_f32_16x16x32_bf16(
            a0k1, bfr[nf][1], acc[p * 2 + 0][nf], 0, 0, 0);
        acc[p * 2 + 1][nf] = __builtin_amdgcn_mfma_f32_16x16x32_bf16(
            a1k0, bfr[nf][0], acc[p * 2 + 1][nf], 0, 0, 0);
        acc[p * 2 + 1][nf] = __builtin_amdgcn_mfma_f32_16x16x32_bf16(
            a1k1, bfr[nf][1], acc[p * 2 + 1][nf], 0, 0, 0);
      }
      __builtin_amdgcn_s_setprio(0);
      if (p == 1) {
        if (st) asm volatile("s_waitcnt vmcnt(4)" ::: "memory");
        else    asm volatile("s_waitcnt vmcnt(0)" ::: "memory");
      }
      if (p == 3 && st) asm volatile("s_waitcnt vmcnt(2)" ::: "memory");
      asm volatile("" ::: "memory");
      __builtin_amdgcn_s_barrier();
    }
  }

  #pragma unroll
  for (int mf = 0; mf < 8; mf++)
    #pragma unroll
    for (int nf = 0; nf < 4; nf++)
      #pragma unroll
      for (int r = 0; r < 4; r++) {
        int row = i0 + wr * 128 + mf * 16 + lq * 4 + r;
        int col = j0 + wc * 64 + nf * 16 + lr;
        C[(size_t)row * ldc + col] = acc[mf][nf][r];
      }
}

// ---------------------------------------------------------------------------
// BM=256 x BN=128, BK=64, TRIPLE-buffered counted-vmcnt GEMM (r16-verified).
// Grid = 256 blocks. LDS 144KiB -> 1 block/CU. 8 waves as 2Mx4N (128x32).
// CMODE 1: C bf16 out. CMODE 2: colsum[j] += sum_i tanh(acc).
// One vmcnt(6)+barrier per K-tile; compute kt while kt+1 lands, kt+2 issues.
// ---------------------------------------------------------------------------
template<int CMODE>
__global__ __launch_bounds__(512, 2) void gemm_n128(
    const unsigned short* __restrict__ A, const unsigned short* __restrict__ B,
    void* __restrict__ Cv, float* __restrict__ colsum,
    int K, int lda, int ldb, int ldc)
{
  __shared__ unsigned short sm[3][384 * 64];   // 3 x 48KiB
  const int t = threadIdx.x;
  const int lane = t & 63, wid = t >> 6;
  const int wr = wid >> 2;          // 0..1 (M half: 128 rows)
  const int wc = wid & 3;           // 0..3 (N quarter: 32 cols)
  const int lr = lane & 15, lq = lane >> 4;

  int bx, by;
  {
    int wg = blockIdx.x;
    int x = wg & 7, s = wg >> 3;
    by = (x & 3) * 4 + (s >> 3);
    bx = (x >> 2) * 8 + (s & 7);
  }
  const int i0 = by * 256, j0 = bx * 128;

  const int r_ = t >> 3;
  const int ss_ = ((t & 7) ^ (r_ & 7)) * 8;

  auto issue = [&](int buf, int c, int k0) {
    const unsigned short* M;
    int ld, r0;
    if (c < 4) { M = A; ld = lda; r0 = i0 + c * 64; }
    else       { M = B; ld = ldb; r0 = j0 + (c - 4) * 64; }
    unsigned short* lb = &sm[buf][c * 4096];
    dma16(M + (size_t)(r0 + r_) * ld + k0 + ss_, lb + wid * 512);
  };

  auto frag = [&](const unsigned short* mat, int row, int kh) -> short8 {
    int lb = row * 128 + kh * 64 + (lq << 4);
    int pb = lb ^ ((row & 7) << 4);
    return *(const short8*)((const char*)mat + pb);
  };

  f32x4 acc[8][2];
  #pragma unroll
  for (int a = 0; a < 8; a++)
    #pragma unroll
    for (int b = 0; b < 2; b++) acc[a][b] = (f32x4){0.f, 0.f, 0.f, 0.f};

  #pragma unroll
  for (int c = 0; c < 6; c++) issue(0, c, 0);
  #pragma unroll
  for (int c = 0; c < 6; c++) issue(1, c, 64);
  asm volatile("s_waitcnt vmcnt(6)" ::: "memory");
  __builtin_amdgcn_s_barrier();

  const int NT = K >> 6;
  int cur = 0;
  for (int kt = 0; kt < NT; kt++) {
    const unsigned short* As = sm[cur];
    const unsigned short* Bs = sm[cur] + 256 * 64;
    const int b2 = (cur + 2 >= 3) ? cur - 1 : cur + 2;
    const int kn = (kt + 2) << 6;
    const bool st = (kt + 2 < NT);

    short8 af[4][2], bfr[2][2];
    #pragma unroll
    for (int m = 0; m < 4; m++) {
      af[m][0] = frag(As, wr * 128 + m * 16 + lr, 0);
      af[m][1] = frag(As, wr * 128 + m * 16 + lr, 1);
    }
    #pragma unroll
    for (int n = 0; n < 2; n++) {
      bfr[n][0] = frag(Bs, wc * 32 + n * 16 + lr, 0);
      bfr[n][1] = frag(Bs, wc * 32 + n * 16 + lr, 1);
    }
    if (st) {
      issue(b2, 0, kn); issue(b2, 2, kn);
      issue(b2, 4, kn); issue(b2, 5, kn);
    }
    __builtin_amdgcn_s_setprio(1);
    #pragma unroll
    for (int m = 0; m < 4; m++)
      #pragma unroll
      for (int n = 0; n < 2; n++) {
        acc[m][n] = __builtin_amdgcn_mfma_f32_16x16x32_bf16(
            af[m][0], bfr[n][0], acc[m][n], 0, 0, 0);
        acc[m][n] = __builtin_amdgcn_mfma_f32_16x16x32_bf16(
            af[m][1], bfr[n][1], acc[m][n], 0, 0, 0);
      }
    __builtin_amdgcn_s_setprio(0);

    #pragma unroll
    for (int m = 0; m < 4; m++) {
      af[m][0] = frag(As, wr * 128 + (4 + m) * 16 + lr, 0);
      af[m][1] = frag(As, wr * 128 + (4 + m) * 16 + lr, 1);
    }
    if (st) { issue(b2, 1, kn); issue(b2, 3, kn); }
    __builtin_amdgcn_s_setprio(1);
    #pragma unroll
    for (int m = 0; m < 4; m++)
      #pragma unroll
      for (int n = 0; n < 2; n++) {
        acc[4 + m][n] = __builtin_amdgcn_mfma_f32_16x16x32_bf16(
            af[m][0], bfr[n][0], acc[4 + m][n], 0, 0, 0);
        acc[4 + m][n] = __builtin_amdgcn_mfma_f32_16x16x32_bf16(
            af[m][1], bfr[n][1], acc[4 + m][n], 0, 0, 0);
      }
    __builtin_amdgcn_s_setprio(0);

    if (kt + 1 < NT) {
      if (st) asm volatile("s_waitcnt vmcnt(6)" ::: "memory");
      else    asm volatile("s_waitcnt vmcnt(0)" ::: "memory");
      __builtin_amdgcn_s_barrier();
    }
    cur = (cur + 1 == 3) ? 0 : cur + 1;
  }

  if (CMODE == 2) {
    #pragma unroll
    for (int n = 0; n < 2; n++) {
      float s = 0.f;
      #pragma unroll
      for (int m = 0; m < 8; m++)
        #pragma unroll
        for (int r = 0; r < 4; r++) s += tanhf(acc[m][n][r]);
      s += __shfl_xor(s, 16);
      s += __shfl_xor(s, 32);
      if (lq == 0) atomicAdd(&colsum[j0 + wc * 32 + n * 16 + lr], s);
    }
  } else {
    #pragma unroll
    for (int m = 0; m < 8; m++)
      #pragma unroll
      for (int n = 0; n < 2; n++)
        #pragma unroll
        for (int r = 0; r < 4; r++) {
          int row = i0 + wr * 128 + m * 16 + lq * 4 + r;
          int col = j0 + wc * 32 + n * 16 + lr;
          ((unsigned short*)Cv)[(size_t)row * ldc + col] = f2bf(acc[m][n][r]);
        }
  }
}

// 128x128-tile bf16 MFMA GEMM (legacy path for non-pre tiers / R<4096).
template<int BF32, int CMODE>
__global__ __launch_bounds__(256) void mfma_gemm(
    const unsigned short* __restrict__ Abf, const void* __restrict__ Bv,
    void* __restrict__ Cv, float* __restrict__ colsum,
    int K, int lda, int ldb, int ldc)
{
  __shared__ unsigned short As[128 * 32];
  __shared__ unsigned short Bs[128 * 32];
  const int t = threadIdx.x;
  const int lane = t & 63, wid = t >> 6;
  const int wm = (wid >> 1) * 64, wn = (wid & 1) * 64;
  const int i0 = blockIdx.y * 128, j0 = blockIdx.x * 128;
  const int lr = lane & 15, lq = lane >> 4;

  f32x4 acc[4][4];
  #pragma unroll
  for (int a = 0; a < 4; a++)
    #pragma unroll
    for (int b = 0; b < 4; b++) acc[a][b] = (f32x4){0.f, 0.f, 0.f, 0.f};

  for (int k0 = 0; k0 < K; k0 += 32) {
    #pragma unroll
    for (int u = 0; u < 2; u++) {
      int vid = u * 256 + t;
      int row = vid >> 2, kq = (vid & 3) * 8;
      dma16(Abf + (size_t)(i0 + row) * lda + k0 + kq,
            &As[(u * 256 + wid * 64) * 8]);
    }
    if (BF32 == 0) {
      #pragma unroll
      for (int u = 0; u < 2; u++) {
        int vid = u * 256 + t;
        int row = vid >> 2, kq = (vid & 3) * 8;
        dma16((const unsigned short*)Bv + (size_t)(j0 + row) * ldb + k0 + kq,
              &Bs[(u * 256 + wid * 64) * 8]);
      }
    } else {
      #pragma unroll
      for (int u = 0; u < 2; u++) {
        int vid = u * 256 + t;
        int row = vid >> 2, kq = (vid & 3) * 8;
        const float* s = (const float*)Bv + (size_t)(j0 + row) * ldb + k0 + kq;
        float4 f0 = *(const float4*)s;
        float4 f1 = *(const float4*)(s + 4);
        union { unsigned short h[8]; int4 v; } pk;
        pk.h[0] = f2bf(f0.x); pk.h[1] = f2bf(f0.y);
        pk.h[2] = f2bf(f0.z); pk.h[3] = f2bf(f0.w);
        pk.h[4] = f2bf(f1.x); pk.h[5] = f2bf(f1.y);
        pk.h[6] = f2bf(f1.z); pk.h[7] = f2bf(f1.w);
        *(int4*)&Bs[(size_t)vid * 8] = pk.v;
      }
    }
    __syncthreads();

    short8 af[4], bfr[4];
    #pragma unroll
    for (int tm = 0; tm < 4; tm++)
      af[tm] = *(const short8*)&As[(wm + tm * 16 + lr) * 32 + lq * 8];
    #pragma unroll
    for (int tn = 0; tn < 4; tn++)
      bfr[tn] = *(const short8*)&Bs[(wn + tn * 16 + lr) * 32 + lq * 8];

    #pragma unroll
    for (int tm = 0; tm < 4; tm++)
      #pragma unroll
      for (int tn = 0; tn < 4; tn++)
        acc[tm][tn] = __builtin_amdgcn_mfma_f32_16x16x32_bf16(
            af[tm], bfr[tn], acc[tm][tn], 0, 0, 0);
    __syncthreads();
  }

  if (CMODE == 2) {
    #pragma unroll
    for (int tn = 0; tn < 4; tn++) {
      float s = 0.f;
      #pragma unroll
      for (int tm = 0; tm < 4; tm++)
        #pragma unroll
        for (int r = 0; r < 4; r++) s += tanhf(acc[tm][tn][r]);
      s += __shfl_xor(s, 16);
      s += __shfl_xor(s, 32);
      if (lq == 0) atomicAdd(&colsum[j0 + wn + tn * 16 + lr], s);
    }
  } else {
    #pragma unroll
    for (int tm = 0; tm < 4; tm++)
      #pragma unroll
      for (int tn = 0; tn < 4; tn++)
        #pragma unroll
        for (int r = 0; r < 4; r++) {
          int row = i0 + wm + tm * 16 + lq * 4 + r;
          int col = j0 + wn + tn * 16 + lr;
          if (CMODE == 0)
            ((float*)Cv)[(size_t)row * ldc + col] = acc[tm][tn][r];
          else
            ((unsigned short*)Cv)[(size_t)row * ldc + col] = f2bf(acc[tm][tn][r]);
        }
  }
}

// Fused: Tt[key][l] = bf16(T[l][key]) AND Tb[l][key] = bf16(T[l][key]).
// One 67MB read of T feeds both outputs (r17-verified kernel).
__global__ __launch_bounds__(256) void transpose_cvt_bf16(
    const float* __restrict__ T, unsigned short* __restrict__ Tt,
    unsigned short* __restrict__ Tb)
{
  __shared__ float tile[64][65];
  const int tx = threadIdx.x & 63;
  const int ty = threadIdx.x >> 6;
  const int k0 = blockIdx.x * 64;
  const int l0 = blockIdx.y * 64;
  #pragma unroll
  for (int u = 0; u < 16; u++) {
    int row = ty * 16 + u;
    float v = T[(size_t)(l0 + row) * 4096 + k0 + tx];
    tile[row][tx] = v;
    Tb[(size_t)(l0 + row) * 4096 + k0 + tx] = f2bf(v);
  }
  __syncthreads();
  #pragma unroll
  for (int u = 0; u < 16; u++) {
    int row = ty * 16 + u;
    Tt[(size_t)(k0 + row) * 2048 + l0 + tx] = f2bf(tile[tx][row]);
  }
}

// Tt_bf[key][l] = bf16(T[l][key]) only (tier0 path).
__global__ __launch_bounds__(256) void transpose_bf16(
    const float* __restrict__ T, unsigned short* __restrict__ Tt)
{
  __shared__ float tile[64][65];
  const int tx = threadIdx.x & 63;
  const int ty = threadIdx.x >> 6;
  const int k0 = blockIdx.x * 64;
  const int l0 = blockIdx.y * 64;
  #pragma unroll
  for (int u = 0; u < 16; u++) {
    int row = ty * 16 + u;
    tile[row][tx] = T[(size_t)(l0 + row) * 4096 + k0 + tx];
  }
  __syncthreads();
  #pragma unroll
  for (int u = 0; u < 16; u++) {
    int row = ty * 16 + u;
    Tt[(size_t)(k0 + row) * 2048 + l0 + tx] = f2bf(tile[tx][row]);
  }
}

// out[i] = bf16(in[i]), 8 elements/thread, packed 16B stores.
__global__ __launch_bounds__(256) void cvt_bf16(
    const float* __restrict__ in, unsigned short* __restrict__ out, int n8)
{
  int i = blockIdx.x * 256 + threadIdx.x;
  if (i >= n8) return;
  float4 f0 = ((const float4*)in)[(size_t)i * 2];
  float4 f1 = ((const float4*)in)[(size_t)i * 2 + 1];
  union { unsigned short h[8]; int4 v; } pk;
  pk.h[0] = f2bf(f0.x); pk.h[1] = f2bf(f0.y);
  pk.h[2] = f2bf(f0.z); pk.h[3] = f2bf(f0.w);
  pk.h[4] = f2bf(f1.x); pk.h[5] = f2bf(f1.y);
  pk.h[6] = f2bf(f1.z); pk.h[7] = f2bf(f1.w);
  ((int4*)out)[i] = pk.v;
}

// Row softmax over 4096 fp32, writes bf16 IN PLACE at row start.
__global__ __launch_bounds__(256) void softmax_bf16(float* __restrict__ S)
{
  float* p = S + (size_t)blockIdx.x * 4096;
  const int tid = threadIdx.x;
  float4 v[4];
  #pragma unroll
  for (int u = 0; u < 4; u++) v[u] = ((const float4*)p)[tid * 4 + u];

  float m = -3.4e38f;
  #pragma unroll
  for (int u = 0; u < 4; u++)
    m = fmaxf(m, fmaxf(fmaxf(v[u].x, v[u].y), fmaxf(v[u].z, v[u].w)));
  #pragma unroll
  for (int off = 32; off > 0; off >>= 1) m = fmaxf(m, __shfl_down(m, off, 64));
  __shared__ float redm[4];
  if ((tid & 63) == 0) redm[tid >> 6] = m;
  __syncthreads();
  m = fmaxf(fmaxf(redm[0], redm[1]), fmaxf(redm[2], redm[3]));

  float s = 0.f;
  #pragma unroll
  for (int u = 0; u < 4; u++) {
    v[u].x = __expf(v[u].x - m); v[u].y = __expf(v[u].y - m);
    v[u].z = __expf(v[u].z - m); v[u].w = __expf(v[u].w - m);
    s += v[u].x + v[u].y + v[u].z + v[u].w;
  }
  #pragma unroll
  for (int off = 32; off > 0; off >>= 1) s += __shfl_down(s, off, 64);
  __shared__ float reds[4];
  if ((tid & 63) == 0) reds[tid >> 6] = s;
  __syncthreads();
  s = reds[0] + reds[1] + reds[2] + reds[3];
  const float inv = 1.f / s;

  unsigned short* a = (unsigned short*)p;
  #pragma unroll
  for (int h = 0; h < 2; h++) {
    union { unsigned short u[8]; int4 q; } pk;
    #pragma unroll
    for (int j = 0; j < 2; j++) {
      float4 w = v[h * 2 + j];
      pk.u[j * 4 + 0] = f2bf(w.x * inv); pk.u[j * 4 + 1] = f2bf(w.y * inv);
      pk.u[j * 4 + 2] = f2bf(w.z * inv); pk.u[j * 4 + 3] = f2bf(w.w * inv);
    }
    ((int4*)a)[tid * 2 + h] = pk.q;
  }
}

__global__ void zero_k(float* p, int n)
{
  int i = blockIdx.x * 256 + threadIdx.x;
  if (i < n) p[i] = 0.f;
}

// scores /= max; softmax; -> FP32 out (2048).
__global__ __launch_bounds__(256) void finalize_k(const float* __restrict__ scores,
                                                  float* __restrict__ out)
{
  const int tid = threadIdx.x;
  float s[8];
  #pragma unroll
  for (int u = 0; u < 8; u++) s[u] = scores[tid + u * 256];

  __shared__ float red[4];

  float m = -3.4e38f;
  #pragma unroll
  for (int u = 0; u < 8; u++) m = fmaxf(m, s[u]);
  #pragma unroll
  for (int off = 32; off > 0; off >>= 1) m = fmaxf(m, __shfl_down(m, off, 64));
  if ((tid & 63) == 0) red[tid >> 6] = m;
  __syncthreads();
  m = fmaxf(fmaxf(red[0], red[1]), fmaxf(red[2], red[3]));
  __syncthreads();

  const float inv1 = 1.f / m;
  #pragma unroll
  for (int u = 0; u < 8; u++) s[u] *= inv1;

  float m2 = -3.4e38f;
  #pragma unroll
  for (int u = 0; u < 8; u++) m2 = fmaxf(m2, s[u]);
  #pragma unroll
  for (int off = 32; off > 0; off >>= 1) m2 = fmaxf(m2, __shfl_down(m2, off, 64));
  if ((tid & 63) == 0) red[tid >> 6] = m2;
  __syncthreads();
  m2 = fmaxf(fmaxf(red[0], red[1]), fmaxf(red[2], red[3]));
  __syncthreads();

  float sum = 0.f;
  #pragma unroll
  for (int u = 0; u < 8; u++) { s[u] = expf(s[u] - m2); sum += s[u]; }
  #pragma unroll
  for (int off = 32; off > 0; off >>= 1) sum += __shfl_down(sum, off, 64);
  if ((tid & 63) == 0) red[tid >> 6] = sum;
  __syncthreads();
  sum = red[0] + red[1] + red[2] + red[3];

  const float invs = 1.f / sum;
  #pragma unroll
  for (int u = 0; u < 8; u++)
    out[tid + u * 256] = s[u] * invs;
}

extern "C" void kernel_launch(void* const* d_in, const int* in_sizes, int n_in,
                              void* d_out, int out_size, void* d_ws, size_t ws_size,
                              hipStream_t stream)
{
  const float* T    = (const float*)d_in[0];   // [2048][4096]
  const float* Win  = (const float*)d_in[1];   // [2048][2048] 'ml'
  const float* Wout = (const float*)d_in[2];   // [2048][4096] 'lc'
  float* out = (float*)d_out;

  const size_t FIX1 = 92274688ull + 16384;
  int R = 1024; bool pre = false;
  if      (ws_size >= FIX1 + (size_t)4096 * 16384) { pre = true; R = 4096; }
  else if (ws_size >= FIX1 + (size_t)2048 * 16384) { pre = true; R = 2048; }
  else if (ws_size >= FIX1 + (size_t)1024 * 16384) { pre = true; R = 1024; }

  unsigned short* Tt = (unsigned short*)d_ws;

  if (pre) {
    unsigned short* Tb    = Tt + (size_t)4096 * 2048;
    unsigned short* Winb  = Tb + (size_t)2048 * 4096;
    unsigned short* Woutb = Winb + (size_t)2048 * 2048;
    unsigned short* comb  = Woutb + (size_t)2048 * 4096;
    float* S      = (float*)(comb + (size_t)4096 * 4096);
    float* scores = S + (size_t)R * 4096;

    zero_k<<<8, 256, 0, stream>>>(scores, 2048);
    transpose_cvt_bf16<<<dim3(64, 32), 256, 0, stream>>>(T, Tt, Tb);
    cvt_bf16<<<2048, 256, 0, stream>>>(Win, Winb, 524288);
    cvt_bf16<<<4096, 256, 0, stream>>>(Wout, Woutb, 1048576);

    // GEMM1: Q -> comb[:,2048:]  (M=4096,N=2048,K=2048; 16x16 grid)
    gemm_n128<1><<<256, 512, 0, stream>>>(
        Tt, Winb, comb + 2048, nullptr, 2048, 2048, 2048, 4096);
    for (int c = 0; c < 4096 / R; c++) {
      const size_t d0 = (size_t)c * R;
      if (R == 4096) {
        // GEMM2 (M=N=4096,K=2048): 256^2 counted-vmcnt template (r16)
        gemm256<<<256, 512, 0, stream>>>(
            comb + 2048, Tt, S, 2048, 4096, 2048, 4096);
      } else {
        mfma_gemm<0, 0><<<dim3(32, R / 128), 256, 0, stream>>>(
            comb + d0 * 4096 + 2048, Tt, S, nullptr, 2048, 4096, 2048, 4096);
      }
      softmax_bf16<<<R, 256, 0, stream>>>(S);
      if (R == 4096) {
        // GEMM3 (M=4096,N=2048,K=4096): tri-buffered n128 (r16)
        gemm_n128<1><<<256, 512, 0, stream>>>(
            (unsigned short*)S, Tb, comb, nullptr, 4096, 8192, 4096, 4096);
      } else {
        mfma_gemm<0, 1><<<dim3(16, R / 128), 256, 0, stream>>>(
            (unsigned short*)S, Tb, comb + d0 * 4096, nullptr, 4096, 8192, 4096, 4096);
      }
    }
    // GEMM4 (M=4096,N=2048,K=4096, tanh colsum): tri-buffered n128 (r16)
    gemm_n128<2><<<256, 512, 0, stream>>>(
        comb, Woutb, nullptr, scores, 4096, 4096, 4096, 4096);
    finalize_k<<<1, 256, 0, stream>>>(scores, out);
  } else {
    // tier0: r12 layout (67,117,056 B proven to fit), inline cvt for fp32 B.
    unsigned short* comb = Tt + (size_t)4096 * 2048;
    float* S      = (float*)(comb + (size_t)4096 * 4096);
    float* scores = S + (size_t)1024 * 4096;

    zero_k<<<8, 256, 0, stream>>>(scores, 2048);
    transpose_bf16<<<dim3(64, 32), 256, 0, stream>>>(T, Tt);

    mfma_gemm<1, 1><<<dim3(16, 32), 256, 0, stream>>>(
        Tt, Win, comb + 2048, nullptr, 2048, 2048, 2048, 4096);
    for (int c = 0; c < 4; c++) {
      const size_t d0 = (size_t)c * 1024;
      mfma_gemm<0, 0><<<dim3(32, 8), 256, 0, stream>>>(
          comb + d0 * 4096 + 2048, Tt, S, nullptr, 2048, 4096, 2048, 4096);
      softmax_bf16<<<1024, 256, 0, stream>>>(S);
      mfma_gemm<1, 1><<<dim3(16, 8), 256, 0, stream>>>(
          (unsigned short*)S, T, comb + d0 * 4096, nullptr, 4096, 8192, 4096, 4096);
    }
    mfma_gemm<1, 2><<<dim3(16, 32), 256, 0, stream>>>(
        comb, Wout, nullptr, scores, 4096, 4096, 4096, 4096);
    finalize_k<<<1, 256, 0, stream>>>(scores, out);
  }
}

// Round 11
// 365.501 us; speedup vs baseline: 1.0426x; 1.0143x over previous
//
#include <hip/hip_runtime.h>
#include <hip/hip_bf16.h>
#include <math.h>

// BS=1, L=2048, D=4096. History: r16=362.2us (BEST), r17=371.2, r18=381.1,
// r19=370.7 (transpose_cvt fusion isolated as +8.5us regression; rejected).
// Plateau evidence: GEMM2 = 74.0-74.7us (~920 TF, MfmaUtil 37%) under 3
// different schedules; r18's 20% LDS-traffic cut moved nothing -> limiter
// is latency/sync choreography at 2 waves/SIMD, not LDS/HBM BW.
// r20 (resubmit; r10 was infra flake GPUAcquisitionTimeout — unbenched;
// pre3_k coverage re-audited: exact union of zero_k+cvt(Win)+cvt(Wout)):
// exact r16 configuration + ONE low-risk delta: merged pre-pass dispatch
// (saves 2 launches). Predict ~355-359us, GEMM counters unchanged.

typedef __attribute__((ext_vector_type(8))) short short8;
typedef __attribute__((ext_vector_type(4))) float f32x4;

__device__ __forceinline__ unsigned short f2bf(float f) {
  unsigned u = __float_as_uint(f);
  return (unsigned short)((u + 0x7FFF + ((u >> 16) & 1)) >> 16);  // RNE
}

typedef const __attribute__((address_space(1))) unsigned int* gas_t;
typedef __attribute__((address_space(3))) unsigned int* las_t;
__device__ __forceinline__ void dma16(const unsigned short* g, unsigned short* l)
{
  __builtin_amdgcn_global_load_lds((gas_t)(const void*)g, (las_t)(void*)l,
                                   16, 0, 0);
}

// ---------------------------------------------------------------------------
// 256x256-tile, BK=64, counted-vmcnt 4-phase GEMM (C fp32 out). GEMM2 only.
// Verified r14b/r16/r19: 74.7us, FETCH 49MB, conflicts 0.
// ---------------------------------------------------------------------------
__global__ __launch_bounds__(512, 2) void gemm256(
    const unsigned short* __restrict__ A, const unsigned short* __restrict__ B,
    float* __restrict__ C, int K, int lda, int ldb, int ldc)
{
  __shared__ unsigned short sm[2][2][256 * 64];
  const int t = threadIdx.x;
  const int lane = t & 63;
  const int wid = t >> 6;
  const int wr = wid >> 2;
  const int wc = wid & 3;
  const int lr = lane & 15, lq = lane >> 4;

  int bx, by;
  {
    int wg = blockIdx.x;
    int x = wg & 7, s = wg >> 3;
    by = (x & 3) * 4 + (s >> 3);
    bx = (x >> 2) * 8 + (s & 7);
  }
  const int i0 = by * 256, j0 = bx * 256;

  const int r_ = t >> 3;
  const int ss_ = ((t & 7) ^ (r_ & 7)) * 8;

  auto issue = [&](int buf, int c, int k0) {
    const unsigned short* M;
    int ld, r0;
    if (c < 4) { M = A; ld = lda; r0 = i0 + (c & 3) * 64; }
    else       { M = B; ld = ldb; r0 = j0 + (c & 3) * 64; }
    unsigned short* lb = &sm[buf][c >> 2][(c & 3) * 4096];
    dma16(M + (size_t)(r0 + r_) * ld + k0 + ss_, lb + wid * 512);
  };

  auto frag = [&](const unsigned short* mat, int row, int kh) -> short8 {
    int lb = row * 128 + kh * 64 + (lq << 4);
    int pb = lb ^ ((row & 7) << 4);
    return *(const short8*)((const char*)mat + pb);
  };

  f32x4 acc[8][4];
  #pragma unroll
  for (int a = 0; a < 8; a++)
    #pragma unroll
    for (int b = 0; b < 4; b++) acc[a][b] = (f32x4){0.f, 0.f, 0.f, 0.f};

  issue(0, 0, 0); issue(0, 2, 0);
  issue(0, 4, 0); issue(0, 5, 0);
  issue(0, 6, 0); issue(0, 7, 0);
  issue(0, 1, 0); issue(0, 3, 0);
  asm volatile("s_waitcnt vmcnt(2)" ::: "memory");
  __builtin_amdgcn_s_barrier();

  const int NT = K >> 6;
  for (int kt = 0; kt < NT; kt++) {
    const int cur = kt & 1;
    const unsigned short* As = sm[cur][0];
    const unsigned short* Bs = sm[cur][1];
    const int kn = (kt + 1) << 6;
    const bool st = (kt + 1 < NT);
    short8 bfr[4][2];

    #pragma unroll
    for (int p = 0; p < 4; p++) {
      short8 a0k0 = frag(As, wr * 128 + (p * 2 + 0) * 16 + lr, 0);
      short8 a0k1 = frag(As, wr * 128 + (p * 2 + 0) * 16 + lr, 1);
      short8 a1k0 = frag(As, wr * 128 + (p * 2 + 1) * 16 + lr, 0);
      short8 a1k1 = frag(As, wr * 128 + (p * 2 + 1) * 16 + lr, 1);
      if (p == 0) {
        #pragma unroll
        for (int nf = 0; nf < 4; nf++) {
          bfr[nf][0] = frag(Bs, wc * 64 + nf * 16 + lr, 0);
          bfr[nf][1] = frag(Bs, wc * 64 + nf * 16 + lr, 1);
        }
      }
      if (st) {
        if (p == 0) { issue(cur ^ 1, 0, kn); issue(cur ^ 1, 2, kn); }
        if (p == 1) { issue(cur ^ 1, 4, kn); issue(cur ^ 1, 5, kn); }
        if (p == 2) { issue(cur ^ 1, 6, kn); issue(cur ^ 1, 7, kn); }
        if (p == 3) { issue(cur ^ 1, 1, kn); issue(cur ^ 1, 3, kn); }
      }
      asm volatile("" ::: "memory");
      __builtin_amdgcn_s_barrier();
      __builtin_amdgcn_s_setprio(1);
      #pragma unroll
      for (int nf = 0; nf < 4; nf++) {
        acc[p * 2 + 0][nf] = __builtin_amdgcn_mfma_f32_16x16x32_bf16(
            a0k0, bfr[nf][0], acc[p * 2 + 0][nf], 0, 0, 0);
        acc[p * 2 + 0][nf] = __builtin_amdgcn_mfma_f32_16x16x32_bf16(
            a0k1, bfr[nf][1], acc[p * 2 + 0][nf], 0, 0, 0);
        acc[p * 2 + 1][nf] = __builtin_amdgcn_mfma_f32_16x16x32_bf16(
            a1k0, bfr[nf][0], acc[p * 2 + 1][nf], 0, 0, 0);
        acc[p * 2 + 1][nf] = __builtin_amdgcn_mfma_f32_16x16x32_bf16(
            a1k1, bfr[nf][1], acc[p * 2 + 1][nf], 0, 0, 0);
      }
      __builtin_amdgcn_s_setprio(0);
      if (p == 1) {
        if (st) asm volatile("s_waitcnt vmcnt(4)" ::: "memory");
        else    asm volatile("s_waitcnt vmcnt(0)" ::: "memory");
      }
      if (p == 3 && st) asm volatile("s_waitcnt vmcnt(2)" ::: "memory");
      asm volatile("" ::: "memory");
      __builtin_amdgcn_s_barrier();
    }
  }

  #pragma unroll
  for (int mf = 0; mf < 8; mf++)
    #pragma unroll
    for (int nf = 0; nf < 4; nf++)
      #pragma unroll
      for (int r = 0; r < 4; r++) {
        int row = i0 + wr * 128 + mf * 16 + lq * 4 + r;
        int col = j0 + wc * 64 + nf * 16 + lr;
        C[(size_t)row * ldc + col] = acc[mf][nf][r];
      }
}

// ---------------------------------------------------------------------------
// BM=256 x BN=128, BK=64, TRIPLE-buffered counted-vmcnt GEMM (r16-verified).
// Grid = 256 blocks. LDS 144KiB -> 1 block/CU. 8 waves as 2Mx4N (128x32).
// CMODE 1: C bf16 out. CMODE 2: colsum[j] += sum_i tanh(acc).
// One vmcnt(6)+barrier per K-tile; compute kt while kt+1 lands, kt+2 issues.
// ---------------------------------------------------------------------------
template<int CMODE>
__global__ __launch_bounds__(512, 2) void gemm_n128(
    const unsigned short* __restrict__ A, const unsigned short* __restrict__ B,
    void* __restrict__ Cv, float* __restrict__ colsum,
    int K, int lda, int ldb, int ldc)
{
  __shared__ unsigned short sm[3][384 * 64];   // 3 x 48KiB
  const int t = threadIdx.x;
  const int lane = t & 63, wid = t >> 6;
  const int wr = wid >> 2;          // 0..1 (M half: 128 rows)
  const int wc = wid & 3;           // 0..3 (N quarter: 32 cols)
  const int lr = lane & 15, lq = lane >> 4;

  int bx, by;
  {
    int wg = blockIdx.x;
    int x = wg & 7, s = wg >> 3;
    by = (x & 3) * 4 + (s >> 3);
    bx = (x >> 2) * 8 + (s & 7);
  }
  const int i0 = by * 256, j0 = bx * 128;

  const int r_ = t >> 3;
  const int ss_ = ((t & 7) ^ (r_ & 7)) * 8;

  auto issue = [&](int buf, int c, int k0) {
    const unsigned short* M;
    int ld, r0;
    if (c < 4) { M = A; ld = lda; r0 = i0 + c * 64; }
    else       { M = B; ld = ldb; r0 = j0 + (c - 4) * 64; }
    unsigned short* lb = &sm[buf][c * 4096];
    dma16(M + (size_t)(r0 + r_) * ld + k0 + ss_, lb + wid * 512);
  };

  auto frag = [&](const unsigned short* mat, int row, int kh) -> short8 {
    int lb = row * 128 + kh * 64 + (lq << 4);
    int pb = lb ^ ((row & 7) << 4);
    return *(const short8*)((const char*)mat + pb);
  };

  f32x4 acc[8][2];
  #pragma unroll
  for (int a = 0; a < 8; a++)
    #pragma unroll
    for (int b = 0; b < 2; b++) acc[a][b] = (f32x4){0.f, 0.f, 0.f, 0.f};

  #pragma unroll
  for (int c = 0; c < 6; c++) issue(0, c, 0);
  #pragma unroll
  for (int c = 0; c < 6; c++) issue(1, c, 64);
  asm volatile("s_waitcnt vmcnt(6)" ::: "memory");
  __builtin_amdgcn_s_barrier();

  const int NT = K >> 6;
  int cur = 0;
  for (int kt = 0; kt < NT; kt++) {
    const unsigned short* As = sm[cur];
    const unsigned short* Bs = sm[cur] + 256 * 64;
    const int b2 = (cur + 2 >= 3) ? cur - 1 : cur + 2;
    const int kn = (kt + 2) << 6;
    const bool st = (kt + 2 < NT);

    short8 af[4][2], bfr[2][2];
    #pragma unroll
    for (int m = 0; m < 4; m++) {
      af[m][0] = frag(As, wr * 128 + m * 16 + lr, 0);
      af[m][1] = frag(As, wr * 128 + m * 16 + lr, 1);
    }
    #pragma unroll
    for (int n = 0; n < 2; n++) {
      bfr[n][0] = frag(Bs, wc * 32 + n * 16 + lr, 0);
      bfr[n][1] = frag(Bs, wc * 32 + n * 16 + lr, 1);
    }
    if (st) {
      issue(b2, 0, kn); issue(b2, 2, kn);
      issue(b2, 4, kn); issue(b2, 5, kn);
    }
    __builtin_amdgcn_s_setprio(1);
    #pragma unroll
    for (int m = 0; m < 4; m++)
      #pragma unroll
      for (int n = 0; n < 2; n++) {
        acc[m][n] = __builtin_amdgcn_mfma_f32_16x16x32_bf16(
            af[m][0], bfr[n][0], acc[m][n], 0, 0, 0);
        acc[m][n] = __builtin_amdgcn_mfma_f32_16x16x32_bf16(
            af[m][1], bfr[n][1], acc[m][n], 0, 0, 0);
      }
    __builtin_amdgcn_s_setprio(0);

    #pragma unroll
    for (int m = 0; m < 4; m++) {
      af[m][0] = frag(As, wr * 128 + (4 + m) * 16 + lr, 0);
      af[m][1] = frag(As, wr * 128 + (4 + m) * 16 + lr, 1);
    }
    if (st) { issue(b2, 1, kn); issue(b2, 3, kn); }
    __builtin_amdgcn_s_setprio(1);
    #pragma unroll
    for (int m = 0; m < 4; m++)
      #pragma unroll
      for (int n = 0; n < 2; n++) {
        acc[4 + m][n] = __builtin_amdgcn_mfma_f32_16x16x32_bf16(
            af[m][0], bfr[n][0], acc[4 + m][n], 0, 0, 0);
        acc[4 + m][n] = __builtin_amdgcn_mfma_f32_16x16x32_bf16(
            af[m][1], bfr[n][1], acc[4 + m][n], 0, 0, 0);
      }
    __builtin_amdgcn_s_setprio(0);

    if (kt + 1 < NT) {
      if (st) asm volatile("s_waitcnt vmcnt(6)" ::: "memory");
      else    asm volatile("s_waitcnt vmcnt(0)" ::: "memory");
      __builtin_amdgcn_s_barrier();
    }
    cur = (cur + 1 == 3) ? 0 : cur + 1;
  }

  if (CMODE == 2) {
    #pragma unroll
    for (int n = 0; n < 2; n++) {
      float s = 0.f;
      #pragma unroll
      for (int m = 0; m < 8; m++)
        #pragma unroll
        for (int r = 0; r < 4; r++) s += tanhf(acc[m][n][r]);
      s += __shfl_xor(s, 16);
      s += __shfl_xor(s, 32);
      if (lq == 0) atomicAdd(&colsum[j0 + wc * 32 + n * 16 + lr], s);
    }
  } else {
    #pragma unroll
    for (int m = 0; m < 8; m++)
      #pragma unroll
      for (int n = 0; n < 2; n++)
        #pragma unroll
        for (int r = 0; r < 4; r++) {
          int row = i0 + wr * 128 + m * 16 + lq * 4 + r;
          int col = j0 + wc * 32 + n * 16 + lr;
          ((unsigned short*)Cv)[(size_t)row * ldc + col] = f2bf(acc[m][n][r]);
        }
  }
}

// 128x128-tile bf16 MFMA GEMM (legacy path for non-pre tiers / R<4096).
template<int BF32, int CMODE>
__global__ __launch_bounds__(256) void mfma_gemm(
    const unsigned short* __restrict__ Abf, const void* __restrict__ Bv,
    void* __restrict__ Cv, float* __restrict__ colsum,
    int K, int lda, int ldb, int ldc)
{
  __shared__ unsigned short As[128 * 32];
  __shared__ unsigned short Bs[128 * 32];
  const int t = threadIdx.x;
  const int lane = t & 63, wid = t >> 6;
  const int wm = (wid >> 1) * 64, wn = (wid & 1) * 64;
  const int i0 = blockIdx.y * 128, j0 = blockIdx.x * 128;
  const int lr = lane & 15, lq = lane >> 4;

  f32x4 acc[4][4];
  #pragma unroll
  for (int a = 0; a < 4; a++)
    #pragma unroll
    for (int b = 0; b < 4; b++) acc[a][b] = (f32x4){0.f, 0.f, 0.f, 0.f};

  for (int k0 = 0; k0 < K; k0 += 32) {
    #pragma unroll
    for (int u = 0; u < 2; u++) {
      int vid = u * 256 + t;
      int row = vid >> 2, kq = (vid & 3) * 8;
      dma16(Abf + (size_t)(i0 + row) * lda + k0 + kq,
            &As[(u * 256 + wid * 64) * 8]);
    }
    if (BF32 == 0) {
      #pragma unroll
      for (int u = 0; u < 2; u++) {
        int vid = u * 256 + t;
        int row = vid >> 2, kq = (vid & 3) * 8;
        dma16((const unsigned short*)Bv + (size_t)(j0 + row) * ldb + k0 + kq,
              &Bs[(u * 256 + wid * 64) * 8]);
      }
    } else {
      #pragma unroll
      for (int u = 0; u < 2; u++) {
        int vid = u * 256 + t;
        int row = vid >> 2, kq = (vid & 3) * 8;
        const float* s = (const float*)Bv + (size_t)(j0 + row) * ldb + k0 + kq;
        float4 f0 = *(const float4*)s;
        float4 f1 = *(const float4*)(s + 4);
        union { unsigned short h[8]; int4 v; } pk;
        pk.h[0] = f2bf(f0.x); pk.h[1] = f2bf(f0.y);
        pk.h[2] = f2bf(f0.z); pk.h[3] = f2bf(f0.w);
        pk.h[4] = f2bf(f1.x); pk.h[5] = f2bf(f1.y);
        pk.h[6] = f2bf(f1.z); pk.h[7] = f2bf(f1.w);
        *(int4*)&Bs[(size_t)vid * 8] = pk.v;
      }
    }
    __syncthreads();

    short8 af[4], bfr[4];
    #pragma unroll
    for (int tm = 0; tm < 4; tm++)
      af[tm] = *(const short8*)&As[(wm + tm * 16 + lr) * 32 + lq * 8];
    #pragma unroll
    for (int tn = 0; tn < 4; tn++)
      bfr[tn] = *(const short8*)&Bs[(wn + tn * 16 + lr) * 32 + lq * 8];

    #pragma unroll
    for (int tm = 0; tm < 4; tm++)
      #pragma unroll
      for (int tn = 0; tn < 4; tn++)
        acc[tm][tn] = __builtin_amdgcn_mfma_f32_16x16x32_bf16(
            af[tm], bfr[tn], acc[tm][tn], 0, 0, 0);
    __syncthreads();
  }

  if (CMODE == 2) {
    #pragma unroll
    for (int tn = 0; tn < 4; tn++) {
      float s = 0.f;
      #pragma unroll
      for (int tm = 0; tm < 4; tm++)
        #pragma unroll
        for (int r = 0; r < 4; r++) s += tanhf(acc[tm][tn][r]);
      s += __shfl_xor(s, 16);
      s += __shfl_xor(s, 32);
      if (lq == 0) atomicAdd(&colsum[j0 + wn + tn * 16 + lr], s);
    }
  } else {
    #pragma unroll
    for (int tm = 0; tm < 4; tm++)
      #pragma unroll
      for (int tn = 0; tn < 4; tn++)
        #pragma unroll
        for (int r = 0; r < 4; r++) {
          int row = i0 + wm + tm * 16 + lq * 4 + r;
          int col = j0 + wn + tn * 16 + lr;
          if (CMODE == 0)
            ((float*)Cv)[(size_t)row * ldc + col] = acc[tm][tn][r];
          else
            ((unsigned short*)Cv)[(size_t)row * ldc + col] = f2bf(acc[tm][tn][r]);
        }
  }
}

// Tt_bf[key][l] = bf16(T[l][key]); T [2048][4096] fp32. (r16-verified)
__global__ __launch_bounds__(256) void transpose_bf16(
    const float* __restrict__ T, unsigned short* __restrict__ Tt)
{
  __shared__ float tile[64][65];
  const int tx = threadIdx.x & 63;
  const int ty = threadIdx.x >> 6;
  const int k0 = blockIdx.x * 64;
  const int l0 = blockIdx.y * 64;
  #pragma unroll
  for (int u = 0; u < 16; u++) {
    int row = ty * 16 + u;
    tile[row][tx] = T[(size_t)(l0 + row) * 4096 + k0 + tx];
  }
  __syncthreads();
  #pragma unroll
  for (int u = 0; u < 16; u++) {
    int row = ty * 16 + u;
    Tt[(size_t)(k0 + row) * 2048 + l0 + tx] = f2bf(tile[tx][row]);
  }
}

// out[i] = bf16(in[i]), 8 elements/thread, packed 16B stores. (r16-verified)
__global__ __launch_bounds__(256) void cvt_bf16(
    const float* __restrict__ in, unsigned short* __restrict__ out, int n8)
{
  int i = blockIdx.x * 256 + threadIdx.x;
  if (i >= n8) return;
  float4 f0 = ((const float4*)in)[(size_t)i * 2];
  float4 f1 = ((const float4*)in)[(size_t)i * 2 + 1];
  union { unsigned short h[8]; int4 v; } pk;
  pk.h[0] = f2bf(f0.x); pk.h[1] = f2bf(f0.y);
  pk.h[2] = f2bf(f0.z); pk.h[3] = f2bf(f0.w);
  pk.h[4] = f2bf(f1.x); pk.h[5] = f2bf(f1.y);
  pk.h[6] = f2bf(f1.z); pk.h[7] = f2bf(f1.w);
  ((int4*)out)[i] = pk.v;
}

// r20: merged pre-pass — blocks [0,2048) cvt Win, [2048,6144) cvt Wout,
// block 6144 zeroes scores. Same math as the three r16 dispatches.
__global__ __launch_bounds__(256) void pre3_k(
    const float* __restrict__ Win, unsigned short* __restrict__ Winb,
    const float* __restrict__ Wout, unsigned short* __restrict__ Woutb,
    float* __restrict__ scores)
{
  const int b = blockIdx.x, t = threadIdx.x;
  const float* in;
  unsigned short* outp;
  int i;
  if (b < 2048)      { in = Win;  outp = Winb;  i = b * 256 + t; }
  else if (b < 6144) { in = Wout; outp = Woutb; i = (b - 2048) * 256 + t; }
  else {
    #pragma unroll
    for (int u = 0; u < 8; u++) scores[t + u * 256] = 0.f;
    return;
  }
  float4 f0 = ((const float4*)in)[(size_t)i * 2];
  float4 f1 = ((const float4*)in)[(size_t)i * 2 + 1];
  union { unsigned short h[8]; int4 v; } pk;
  pk.h[0] = f2bf(f0.x); pk.h[1] = f2bf(f0.y);
  pk.h[2] = f2bf(f0.z); pk.h[3] = f2bf(f0.w);
  pk.h[4] = f2bf(f1.x); pk.h[5] = f2bf(f1.y);
  pk.h[6] = f2bf(f1.z); pk.h[7] = f2bf(f1.w);
  ((int4*)outp)[i] = pk.v;
}

// Row softmax over 4096 fp32, writes bf16 IN PLACE at row start.
__global__ __launch_bounds__(256) void softmax_bf16(float* __restrict__ S)
{
  float* p = S + (size_t)blockIdx.x * 4096;
  const int tid = threadIdx.x;
  float4 v[4];
  #pragma unroll
  for (int u = 0; u < 4; u++) v[u] = ((const float4*)p)[tid * 4 + u];

  float m = -3.4e38f;
  #pragma unroll
  for (int u = 0; u < 4; u++)
    m = fmaxf(m, fmaxf(fmaxf(v[u].x, v[u].y), fmaxf(v[u].z, v[u].w)));
  #pragma unroll
  for (int off = 32; off > 0; off >>= 1) m = fmaxf(m, __shfl_down(m, off, 64));
  __shared__ float redm[4];
  if ((tid & 63) == 0) redm[tid >> 6] = m;
  __syncthreads();
  m = fmaxf(fmaxf(redm[0], redm[1]), fmaxf(redm[2], redm[3]));

  float s = 0.f;
  #pragma unroll
  for (int u = 0; u < 4; u++) {
    v[u].x = __expf(v[u].x - m); v[u].y = __expf(v[u].y - m);
    v[u].z = __expf(v[u].z - m); v[u].w = __expf(v[u].w - m);
    s += v[u].x + v[u].y + v[u].z + v[u].w;
  }
  #pragma unroll
  for (int off = 32; off > 0; off >>= 1) s += __shfl_down(s, off, 64);
  __shared__ float reds[4];
  if ((tid & 63) == 0) reds[tid >> 6] = s;
  __syncthreads();
  s = reds[0] + reds[1] + reds[2] + reds[3];
  const float inv = 1.f / s;

  unsigned short* a = (unsigned short*)p;
  #pragma unroll
  for (int h = 0; h < 2; h++) {
    union { unsigned short u[8]; int4 q; } pk;
    #pragma unroll
    for (int j = 0; j < 2; j++) {
      float4 w = v[h * 2 + j];
      pk.u[j * 4 + 0] = f2bf(w.x * inv); pk.u[j * 4 + 1] = f2bf(w.y * inv);
      pk.u[j * 4 + 2] = f2bf(w.z * inv); pk.u[j * 4 + 3] = f2bf(w.w * inv);
    }
    ((int4*)a)[tid * 2 + h] = pk.q;
  }
}

__global__ void zero_k(float* p, int n)
{
  int i = blockIdx.x * 256 + threadIdx.x;
  if (i < n) p[i] = 0.f;
}

// scores /= max; softmax; -> FP32 out (2048).
__global__ __launch_bounds__(256) void finalize_k(const float* __restrict__ scores,
                                                  float* __restrict__ out)
{
  const int tid = threadIdx.x;
  float s[8];
  #pragma unroll
  for (int u = 0; u < 8; u++) s[u] = scores[tid + u * 256];

  __shared__ float red[4];

  float m = -3.4e38f;
  #pragma unroll
  for (int u = 0; u < 8; u++) m = fmaxf(m, s[u]);
  #pragma unroll
  for (int off = 32; off > 0; off >>= 1) m = fmaxf(m, __shfl_down(m, off, 64));
  if ((tid & 63) == 0) red[tid >> 6] = m;
  __syncthreads();
  m = fmaxf(fmaxf(red[0], red[1]), fmaxf(red[2], red[3]));
  __syncthreads();

  const float inv1 = 1.f / m;
  #pragma unroll
  for (int u = 0; u < 8; u++) s[u] *= inv1;

  float m2 = -3.4e38f;
  #pragma unroll
  for (int u = 0; u < 8; u++) m2 = fmaxf(m2, s[u]);
  #pragma unroll
  for (int off = 32; off > 0; off >>= 1) m2 = fmaxf(m2, __shfl_down(m2, off, 64));
  if ((tid & 63) == 0) red[tid >> 6] = m2;
  __syncthreads();
  m2 = fmaxf(fmaxf(red[0], red[1]), fmaxf(red[2], red[3]));
  __syncthreads();

  float sum = 0.f;
  #pragma unroll
  for (int u = 0; u < 8; u++) { s[u] = expf(s[u] - m2); sum += s[u]; }
  #pragma unroll
  for (int off = 32; off > 0; off >>= 1) sum += __shfl_down(sum, off, 64);
  if ((tid & 63) == 0) red[tid >> 6] = sum;
  __syncthreads();
  sum = red[0] + red[1] + red[2] + red[3];

  const float invs = 1.f / sum;
  #pragma unroll
  for (int u = 0; u < 8; u++)
    out[tid + u * 256] = s[u] * invs;
}

extern "C" void kernel_launch(void* const* d_in, const int* in_sizes, int n_in,
                              void* d_out, int out_size, void* d_ws, size_t ws_size,
                              hipStream_t stream)
{
  const float* T    = (const float*)d_in[0];   // [2048][4096]
  const float* Win  = (const float*)d_in[1];   // [2048][2048] 'ml'
  const float* Wout = (const float*)d_in[2];   // [2048][4096] 'lc'
  float* out = (float*)d_out;

  const size_t FIX1 = 92274688ull + 16384;
  int R = 1024; bool pre = false;
  if      (ws_size >= FIX1 + (size_t)4096 * 16384) { pre = true; R = 4096; }
  else if (ws_size >= FIX1 + (size_t)2048 * 16384) { pre = true; R = 2048; }
  else if (ws_size >= FIX1 + (size_t)1024 * 16384) { pre = true; R = 1024; }

  unsigned short* Tt = (unsigned short*)d_ws;

  if (pre) {
    unsigned short* Tb    = Tt + (size_t)4096 * 2048;
    unsigned short* Winb  = Tb + (size_t)2048 * 4096;
    unsigned short* Woutb = Winb + (size_t)2048 * 2048;
    unsigned short* comb  = Woutb + (size_t)2048 * 4096;
    float* S      = (float*)(comb + (size_t)4096 * 4096);
    float* scores = S + (size_t)R * 4096;

    // r20 pre-pass: 3 dispatches (was 5 in r16)
    pre3_k<<<6145, 256, 0, stream>>>(Win, Winb, Wout, Woutb, scores);
    transpose_bf16<<<dim3(64, 32), 256, 0, stream>>>(T, Tt);
    cvt_bf16<<<4096, 256, 0, stream>>>(T, Tb, 1048576);

    // GEMM1: Q -> comb[:,2048:]  (M=4096,N=2048,K=2048; 16x16 grid)
    gemm_n128<1><<<256, 512, 0, stream>>>(
        Tt, Winb, comb + 2048, nullptr, 2048, 2048, 2048, 4096);
    for (int c = 0; c < 4096 / R; c++) {
      const size_t d0 = (size_t)c * R;
      if (R == 4096) {
        // GEMM2 (M=N=4096,K=2048): 256^2 counted-vmcnt template (r16)
        gemm256<<<256, 512, 0, stream>>>(
            comb + 2048, Tt, S, 2048, 4096, 2048, 4096);
      } else {
        mfma_gemm<0, 0><<<dim3(32, R / 128), 256, 0, stream>>>(
            comb + d0 * 4096 + 2048, Tt, S, nullptr, 2048, 4096, 2048, 4096);
      }
      softmax_bf16<<<R, 256, 0, stream>>>(S);
      if (R == 4096) {
        // GEMM3 (M=4096,N=2048,K=4096): tri-buffered n128 (r16)
        gemm_n128<1><<<256, 512, 0, stream>>>(
            (unsigned short*)S, Tb, comb, nullptr, 4096, 8192, 4096, 4096);
      } else {
        mfma_gemm<0, 1><<<dim3(16, R / 128), 256, 0, stream>>>(
            (unsigned short*)S, Tb, comb + d0 * 4096, nullptr, 4096, 8192, 4096, 4096);
      }
    }
    // GEMM4 (M=4096,N=2048,K=4096, tanh colsum): tri-buffered n128 (r16)
    gemm_n128<2><<<256, 512, 0, stream>>>(
        comb, Woutb, nullptr, scores, 4096, 4096, 4096, 4096);
    finalize_k<<<1, 256, 0, stream>>>(scores, out);
  } else {
    // tier0: r12 layout (67,117,056 B proven to fit), inline cvt for fp32 B.
    unsigned short* comb = Tt + (size_t)4096 * 2048;
    float* S      = (float*)(comb + (size_t)4096 * 4096);
    float* scores = S + (size_t)1024 * 4096;

    zero_k<<<8, 256, 0, stream>>>(scores, 2048);
    transpose_bf16<<<dim3(64, 32), 256, 0, stream>>>(T, Tt);

    mfma_gemm<1, 1><<<dim3(16, 32), 256, 0, stream>>>(
        Tt, Win, comb + 2048, nullptr, 2048, 2048, 2048, 4096);
    for (int c = 0; c < 4; c++) {
      const size_t d0 = (size_t)c * 1024;
      mfma_gemm<0, 0><<<dim3(32, 8), 256, 0, stream>>>(
          comb + d0 * 4096 + 2048, Tt, S, nullptr, 2048, 4096, 2048, 4096);
      softmax_bf16<<<1024, 256, 0, stream>>>(S);
      mfma_gemm<1, 1><<<dim3(16, 8), 256, 0, stream>>>(
          (unsigned short*)S, T, comb + d0 * 4096, nullptr, 4096, 8192, 4096, 4096);
    }
    mfma_gemm<1, 2><<<dim3(16, 32), 256, 0, stream>>>(
        comb, Wout, nullptr, scores, 4096, 4096, 4096, 4096);
    finalize_k<<<1, 256, 0, stream>>>(scores, out);
  }
}